// Round 10
// baseline (220.934 us; speedup 1.0000x reference)
//
#include <hip/hip_runtime.h>

#define N_NODES 50000
#define E_EDGES 800000
#define FEAT    128
#define KORD    3
#define BN_EPS  1e-5f
#define NB1     49          // ceil(50000/1024) scan blocks
#define NBUK    49          // coarse buckets (dst >> 10)
#define BCAP    20480       // bucket capacity

typedef __fp16 f16x2 __attribute__((ext_vector_type(2)));
typedef __fp16 f16x8 __attribute__((ext_vector_type(8)));
typedef __attribute__((ext_vector_type(4))) float f32x4;

__device__ __forceinline__ unsigned h2u(f16x2 h) { union { f16x2 h; unsigned u; } c; c.h = h; return c.u; }
__device__ __forceinline__ f16x2 u2h(unsigned u) { union { unsigned u; f16x2 h; } c; c.u = u; return c.h; }

// ---- weights prep (f16): Wb[o][i]=W[o][i];  LtT[o][k*128+i]=L[k][i][o] ----
__global__ void wprep(const float* __restrict__ W, const float* __restrict__ L,
                      __fp16* __restrict__ Wb, __fp16* __restrict__ LtT) {
    const int o = blockIdx.x;      // 128
    const int i = threadIdx.x;     // 128
    Wb[o * FEAT + i] = (__fp16)W[o * FEAT + i];
    #pragma unroll
    for (int k = 0; k < KORD; ++k)
        LtT[(size_t)o * 384 + k * FEAT + i] = (__fp16)L[((size_t)k * FEAT + i) * FEAT + o];
}

// ---- per node: feature->f16, and pack {coords, g=attW@f} into 2 float4 ----
__global__ void g_cast(const float* __restrict__ feat,
                       const float* __restrict__ coords,
                       const float* __restrict__ attW,
                       __fp16* __restrict__ fh,
                       float4* __restrict__ pk) {
    const int node = (blockIdx.x * blockDim.x + threadIdx.x) >> 6;
    const int lane = threadIdx.x & 63;
    if (node >= N_NODES) return;
    const float2 f = *(const float2*)(feat + (size_t)node * FEAT + lane * 2);
    *(f16x2*)(fh + (size_t)node * FEAT + lane * 2) = __builtin_amdgcn_cvt_pkrtz(f.x, f.y);
    float gg[3];
    #pragma unroll
    for (int j = 0; j < 3; ++j) {
        float p = f.x * attW[j * FEAT + lane * 2] + f.y * attW[j * FEAT + lane * 2 + 1];
        #pragma unroll
        for (int off = 32; off; off >>= 1) p += __shfl_xor(p, off);
        gg[j] = p;
    }
    if (lane == 0) {
        const float c0 = coords[node * 3 + 0], c1 = coords[node * 3 + 1], c2 = coords[node * 3 + 2];
        pk[2 * node]     = make_float4(c0, c1, c2, gg[0]);
        pk[2 * node + 1] = make_float4(gg[1], gg[2], 0.f, 0.f);
    }
}

// ============ CSR build ============
__global__ __launch_bounds__(256)
void bucketA(const int* __restrict__ src, const int* __restrict__ dst,
             const int* __restrict__ order,
             int* __restrict__ cnt, int* __restrict__ gcur, int2* __restrict__ bbuf) {
    __shared__ int lcnt[NBUK];
    __shared__ int lbase[NBUK];
    const int tid = threadIdx.x;
    if (tid < NBUK) lcnt[tid] = 0;
    __syncthreads();
    const int e0 = blockIdx.x * 2048;
    int b[8], r[8], so[8], dd[8];
    #pragma unroll
    for (int i = 0; i < 8; ++i) {
        const int e = e0 + i * 256 + tid;
        if (e < E_EDGES) {
            dd[i] = dst[e];
            so[i] = (order[e] << 16) | src[e];
            b[i] = dd[i] >> 10;
            r[i] = atomicAdd(&lcnt[b[i]], 1);
            atomicAdd(cnt + dd[i], 1);
        } else b[i] = -1;
    }
    __syncthreads();
    if (tid < NBUK) lbase[tid] = atomicAdd(&gcur[tid], lcnt[tid]);
    __syncthreads();
    #pragma unroll
    for (int i = 0; i < 8; ++i)
        if (b[i] >= 0)
            bbuf[(size_t)b[i] * BCAP + lbase[b[i]] + r[i]] = make_int2(so[i], dd[i]);
}

__global__ __launch_bounds__(256)
void scan1(const int* __restrict__ cnt, int* __restrict__ rowptr, int* __restrict__ bsum) {
    __shared__ int lds[256];
    const int b = blockIdx.x, t = threadIdx.x;
    const int base = b * 1024 + t * 4;
    int v[4];
    #pragma unroll
    for (int i = 0; i < 4; ++i) v[i] = (base + i < N_NODES) ? cnt[base + i] : 0;
    lds[t] = v[0] + v[1] + v[2] + v[3];
    __syncthreads();
    for (int off = 1; off < 256; off <<= 1) {
        const int u = (t >= off) ? lds[t - off] : 0;
        __syncthreads();
        lds[t] += u;
        __syncthreads();
    }
    int excl = t ? lds[t - 1] : 0;
    if (t == 255) bsum[b] = lds[255];
    #pragma unroll
    for (int i = 0; i < 4; ++i) {
        if (base + i < N_NODES) rowptr[base + i] = excl;
        excl += v[i];
    }
}

__global__ void scan2(const int* __restrict__ bsum, int* __restrict__ boff,
                      int* __restrict__ rowptr) {
    const int lane = threadIdx.x;   // 64
    const int v = (lane < NB1) ? bsum[lane] : 0;
    int incl = v;
    #pragma unroll
    for (int off = 1; off < 64; off <<= 1) {
        const int u = __shfl_up(incl, off);
        if (lane >= off) incl += u;
    }
    if (lane < NB1) boff[lane] = incl - v;
    if (lane == 0) rowptr[N_NODES] = E_EDGES;
}

__global__ void scan3(int* __restrict__ rowptr, int* __restrict__ cursor,
                      const int* __restrict__ boff) {
    const int i = blockIdx.x * blockDim.x + threadIdx.x;
    if (i >= N_NODES) return;
    const int v = rowptr[i] + boff[i >> 10];
    rowptr[i] = v;
    cursor[i] = v;
}

__global__ void bucketB(const int* __restrict__ gcur, const int2* __restrict__ bbuf,
                        int* __restrict__ cursor, int* __restrict__ sord_p) {
    const int b = blockIdx.x >> 3;
    const int seg = blockIdx.x & 7;
    const int n = gcur[b];
    const int lo = (int)((long)n * seg / 8), hi = (int)((long)n * (seg + 1) / 8);
    for (int i = lo + (int)threadIdx.x; i < hi; i += 256) {
        const int2 ent = bbuf[(size_t)b * BCAP + i];
        const int pos = atomicAdd(cursor + ent.y, 1);
        sord_p[pos] = ent.x;
    }
}

// ---- fused edge-att + segment softmax + per-order gather-aggregate ----
__global__ void segagg(const float4* __restrict__ pk,
                       const int* __restrict__ sord_p,
                       const int* __restrict__ rowptr,
                       const __fp16* __restrict__ fh,
                       __fp16* __restrict__ agg) {
    __shared__ uint4 stash[4][64];
    const int node = (blockIdx.x * blockDim.x + threadIdx.x) >> 6;
    const int lane = threadIdx.x & 63;
    const int wid  = threadIdx.x >> 6;
    if (node >= N_NODES) return;
    const int beg = rowptr[node], end = rowptr[node + 1];
    const float4 b0 = pk[2 * node];

    float att0 = -1e30f, inv0 = 0.f; int sol0 = 0;
    float m = -1e30f, s = 0.f;
    int nch = 0;
    for (int cb = beg; cb < end; cb += 64, ++nch) {
        const int p = cb + lane;
        float a = -1e30f, iv = 0.f; int so = 0;
        if (p < end) {
            so = sord_p[p];
            const int sn = so & 0xFFFF;
            const float4 a0 = pk[2 * sn], a1 = pk[2 * sn + 1];
            const float dx = a0.x - b0.x, dy = a0.y - b0.y, dz = a0.z - b0.z;
            a = dx * a0.w + dy * a1.x + dz * a1.y;
            iv = 1.f / (dx * dx + dy * dy + dz * dz + 1.f);
        }
        if (nch == 0) { att0 = a; inv0 = iv; sol0 = so; }
        const float mn = fmaxf(m, a);
        s = s * __expf(m - mn) + ((p < end) ? __expf(a - mn) : 0.f);
        m = mn;
    }
    #pragma unroll
    for (int off = 32; off; off >>= 1) {
        const float mo = __shfl_xor(m, off), so_ = __shfl_xor(s, off);
        const float mn = fmaxf(m, mo);
        s = s * __expf(m - mn) + so_ * __expf(mo - mn);
        m = mn;
    }
    const float inv_s = s > 0.f ? 1.f / s : 0.f;

    const int half = lane >> 5;
    const int lsub = lane & 31;
    f16x2 acc00 = {0, 0}, acc01 = {0, 0};
    f16x2 acc10 = {0, 0}, acc11 = {0, 0};
    f16x2 acc20 = {0, 0}, acc21 = {0, 0};

    int ch = 0;
    for (int cb = beg; cb < end; cb += 64, ++ch) {
        const int p = cb + lane;
        float wl = 0.f; int so = 0;
        if (ch == 0) {
            wl = __expf(att0 - m) * inv_s * inv0;
            so = sol0;
        } else if (p < end) {
            so = sord_p[p];
            const int sn = so & 0xFFFF;
            const float4 a0 = pk[2 * sn], a1 = pk[2 * sn + 1];
            const float dx = a0.x - b0.x, dy = a0.y - b0.y, dz = a0.z - b0.z;
            const float a = dx * a0.w + dy * a1.x + dz * a1.y;
            wl = __expf(a - m) * inv_s / (dx * dx + dy * dy + dz * dz + 1.f);
        }
        const int k = so >> 16;
        const __fp16 wh = (__fp16)wl;
        f16x2 w2; w2.x = wh; w2.y = wh;
        const unsigned uw = h2u(w2);
        stash[wid][lane] = make_uint4(k == 0 ? uw : 0u, k == 1 ? uw : 0u,
                                      k == 2 ? uw : 0u, (unsigned)(so & 0xFFFF));
        const int ne = min(64, end - cb);
        const uint4* st = stash[wid];
        for (int t = 0; t < ne; t += 2) {
            const uint4 e = st[t + half];
            const uint2 v = *(const uint2*)((const char*)fh + ((size_t)e.w << 8) + lsub * 8);
            const f16x2 va = u2h(v.x), vb = u2h(v.y);
            acc00 = __builtin_elementwise_fma(va, u2h(e.x), acc00);
            acc01 = __builtin_elementwise_fma(vb, u2h(e.x), acc01);
            acc10 = __builtin_elementwise_fma(va, u2h(e.y), acc10);
            acc11 = __builtin_elementwise_fma(vb, u2h(e.y), acc11);
            acc20 = __builtin_elementwise_fma(va, u2h(e.z), acc20);
            acc21 = __builtin_elementwise_fma(vb, u2h(e.z), acc21);
        }
    }
    acc00 = acc00 + u2h(__shfl_xor((int)h2u(acc00), 32));
    acc01 = acc01 + u2h(__shfl_xor((int)h2u(acc01), 32));
    acc10 = acc10 + u2h(__shfl_xor((int)h2u(acc10), 32));
    acc11 = acc11 + u2h(__shfl_xor((int)h2u(acc11), 32));
    acc20 = acc20 + u2h(__shfl_xor((int)h2u(acc20), 32));
    acc21 = acc21 + u2h(__shfl_xor((int)h2u(acc21), 32));
    if (lane < 32) {
        __fp16* row = agg + (size_t)node * 384 + lsub * 4;
        *(uint2*)(row)       = make_uint2(h2u(acc00), h2u(acc01));
        *(uint2*)(row + 128) = make_uint2(h2u(acc10), h2u(acc11));
        *(uint2*)(row + 256) = make_uint2(h2u(acc20), h2u(acc21));
    }
}

// ============================================================================
// gemm1: h[m,o] = sum_{ki<384} agg[m,ki] * LtT[o,ki]   (f16 out)
// 64-row M-tile, 256 thr (4 waves x 16 rows), 48KB LDS, 782 blocks.
// ============================================================================
__global__ __launch_bounds__(256)
void gemm1(const __fp16* __restrict__ agg, const __fp16* __restrict__ LtT,
           __fp16* __restrict__ h, int M) {
    __shared__ char smem[49152];          // As[64][128] 16KB | Bs[128][128] 32KB
    char* As = smem;
    char* Bs = smem + 16384;
    const int m0 = blockIdx.x * 64;
    const int tid = threadIdx.x;
    const int wave = tid >> 6, lane = tid & 63;
    const int wm0 = wave * 16;
    const int lrow = lane & 15;
    const int kslot = (lane >> 4) << 4;
    const int swz = (lrow & 7) << 4;

    f32x4 acc[8];
    #pragma unroll
    for (int b = 0; b < 8; ++b) acc[b] = (f32x4){0.f, 0.f, 0.f, 0.f};

    for (int kc = 0; kc < 3; ++kc) {
        __syncthreads();
        #pragma unroll
        for (int p = tid; p < 1024; p += 256) {       // A: 4 float4/thread
            const int row = p >> 4, c = p & 15;
            const int off = ((row << 8) + (c << 4)) ^ ((row & 7) << 4);
            float4 v = make_float4(0.f, 0.f, 0.f, 0.f);
            if (m0 + row < M)
                v = *(const float4*)(agg + (size_t)(m0 + row) * 384 + kc * 128 + c * 8);
            *(float4*)(As + off) = v;
        }
        #pragma unroll
        for (int p = tid; p < 2048; p += 256) {       // B: 8 float4/thread
            const int row = p >> 4, c = p & 15;
            const int off = ((row << 8) + (c << 4)) ^ ((row & 7) << 4);
            *(float4*)(Bs + off) = *(const float4*)(LtT + (size_t)row * 384 + kc * 128 + c * 8);
        }
        __syncthreads();
        f16x8 afr[4];
        #pragma unroll
        for (int ks = 0; ks < 4; ++ks) {
            const int row = wm0 + lrow;
            afr[ks] = *(const f16x8*)(As + (((row << 8) + (ks << 6) + kslot) ^ swz));
        }
        #pragma unroll
        for (int nf = 0; nf < 8; ++nf) {
            #pragma unroll
            for (int ks = 0; ks < 4; ++ks) {
                const int row = nf * 16 + lrow;
                f16x8 bfr = *(const f16x8*)(Bs + (((row << 8) + (ks << 6) + kslot) ^ swz));
                acc[nf] = __builtin_amdgcn_mfma_f32_16x16x32_f16(afr[ks], bfr, acc[nf], 0, 0, 0);
            }
        }
    }
    #pragma unroll
    for (int nf = 0; nf < 8; ++nf)
        #pragma unroll
        for (int rg = 0; rg < 4; ++rg) {
            const int row = m0 + wm0 + (lane >> 4) * 4 + rg;
            if (row < M) h[(size_t)row * FEAT + nf * 16 + lrow] = (__fp16)acc[nf][rg];
        }
}

// ============================================================================
// gemm2: y[m,o] = relu(sum_i h[m,i]*Wb[o,i] + b[o])  (f32 out) + BN stats
// 64-row M-tile, K=128, 48KB LDS, 782 blocks.
// ============================================================================
__global__ __launch_bounds__(256)
void gemm2(const __fp16* __restrict__ h, const __fp16* __restrict__ Wb,
           float* __restrict__ out, int M,
           const float* __restrict__ bias, float* __restrict__ sbuf) {
    __shared__ char smem[49152];
    char* As = smem;
    char* Bs = smem + 16384;
    const int m0 = blockIdx.x * 64;
    const int tid = threadIdx.x;
    const int wave = tid >> 6, lane = tid & 63;
    const int wm0 = wave * 16;
    const int lrow = lane & 15;
    const int kslot = (lane >> 4) << 4;
    const int swz = (lrow & 7) << 4;

    #pragma unroll
    for (int p = tid; p < 1024; p += 256) {
        const int row = p >> 4, c = p & 15;
        const int off = ((row << 8) + (c << 4)) ^ ((row & 7) << 4);
        float4 v = make_float4(0.f, 0.f, 0.f, 0.f);
        if (m0 + row < M) v = *(const float4*)(h + (size_t)(m0 + row) * FEAT + c * 8);
        *(float4*)(As + off) = v;
    }
    #pragma unroll
    for (int p = tid; p < 2048; p += 256) {
        const int row = p >> 4, c = p & 15;
        const int off = ((row << 8) + (c << 4)) ^ ((row & 7) << 4);
        *(float4*)(Bs + off) = *(const float4*)(Wb + (size_t)row * FEAT + c * 8);
    }
    __syncthreads();

    f32x4 acc[8];
    #pragma unroll
    for (int b = 0; b < 8; ++b) acc[b] = (f32x4){0.f, 0.f, 0.f, 0.f};
    f16x8 afr[4];
    #pragma unroll
    for (int ks = 0; ks < 4; ++ks) {
        const int row = wm0 + lrow;
        afr[ks] = *(const f16x8*)(As + (((row << 8) + (ks << 6) + kslot) ^ swz));
    }
    #pragma unroll
    for (int nf = 0; nf < 8; ++nf) {
        #pragma unroll
        for (int ks = 0; ks < 4; ++ks) {
            const int row = nf * 16 + lrow;
            f16x8 bfr = *(const f16x8*)(Bs + (((row << 8) + (ks << 6) + kslot) ^ swz));
            acc[nf] = __builtin_amdgcn_mfma_f32_16x16x32_f16(afr[ks], bfr, acc[nf], 0, 0, 0);
        }
    }

    float s[8], s2[8], bv[8];
    #pragma unroll
    for (int nf = 0; nf < 8; ++nf) { s[nf] = 0.f; s2[nf] = 0.f; bv[nf] = bias[nf * 16 + lrow]; }
    #pragma unroll
    for (int nf = 0; nf < 8; ++nf)
        #pragma unroll
        for (int rg = 0; rg < 4; ++rg) {
            const int row = m0 + wm0 + (lane >> 4) * 4 + rg;
            if (row < M) {
                const float v = fmaxf(acc[nf][rg] + bv[nf], 0.f);
                out[(size_t)row * FEAT + nf * 16 + lrow] = v;
                s[nf] += v;
                s2[nf] = fmaf(v, v, s2[nf]);
            }
        }
    #pragma unroll
    for (int nf = 0; nf < 8; ++nf) {
        s[nf]  += __shfl_xor(s[nf], 16);  s[nf]  += __shfl_xor(s[nf], 32);
        s2[nf] += __shfl_xor(s2[nf], 16); s2[nf] += __shfl_xor(s2[nf], 32);
    }
    __syncthreads();
    float* red = (float*)smem;                // [4][256]
    if (lane < 16) {
        #pragma unroll
        for (int nf = 0; nf < 8; ++nf) {
            red[wave * 256 + nf * 16 + lane]       = s[nf];
            red[wave * 256 + 128 + nf * 16 + lane] = s2[nf];
        }
    }
    __syncthreads();
    if (tid < 128) {
        const float ss = red[tid] + red[256 + tid] + red[512 + tid] + red[768 + tid];
        const float qq = red[128 + tid] + red[384 + tid] + red[640 + tid] + red[896 + tid];
        atomicAdd(sbuf + tid, ss);
        atomicAdd(sbuf + FEAT + tid, qq);
    }
}

// ---- BN normalize (finalize fused: each block derives scale/shift) ----
__global__ void normalize(float* __restrict__ y, const float* __restrict__ sbuf,
                          const float* __restrict__ gamma, const float* __restrict__ beta) {
    __shared__ float sc_s[FEAT], sh_s[FEAT];
    const int t = threadIdx.x;
    if (t < FEAT) {
        const float mean = sbuf[t] / (float)N_NODES;
        const float var  = sbuf[FEAT + t] / (float)N_NODES - mean * mean;
        const float sc   = gamma[t] * rsqrtf(var + BN_EPS);
        sc_s[t] = sc;
        sh_s[t] = beta[t] - mean * sc;
    }
    __syncthreads();
    const int idx = blockIdx.x * blockDim.x + t;
    const int o4 = (idx & 31) * 4;
    float4 v = *(float4*)(y + (size_t)idx * 4);
    const float4 sc = *(const float4*)(sc_s + o4);
    const float4 sh = *(const float4*)(sh_s + o4);
    v.x = fmaf(v.x, sc.x, sh.x);
    v.y = fmaf(v.y, sc.y, sh.y);
    v.z = fmaf(v.z, sc.z, sh.z);
    v.w = fmaf(v.w, sc.w, sh.w);
    *(float4*)(y + (size_t)idx * 4) = v;
}

extern "C" void kernel_launch(void* const* d_in, const int* in_sizes, int n_in,
                              void* d_out, int out_size, void* d_ws, size_t ws_size,
                              hipStream_t stream) {
    const float* feature = (const float*)d_in[0];
    const float* coords  = (const float*)d_in[1];
    const int*   src     = (const int*)d_in[2];
    const int*   dst     = (const int*)d_in[3];
    const int*   order   = (const int*)d_in[4];
    const float* linear  = (const float*)d_in[5];
    const float* attW    = (const float*)d_in[6];
    const float* mlp_w   = (const float*)d_in[7];
    const float* mlp_b   = (const float*)d_in[8];
    const float* gamma   = (const float*)d_in[9];
    const float* beta    = (const float*)d_in[10];
    float* out = (float*)d_out;

    char* p = (char*)d_ws;
    __fp16* fh           = (__fp16*)p;  p += (size_t)N_NODES * FEAT * 2;   // 12.8 MB
    __fp16* agg          = (__fp16*)p;  p += (size_t)N_NODES * 384 * 2;    // 38.4 MB
    __fp16* hbuf         = (__fp16*)p;  p += (size_t)N_NODES * FEAT * 2;   // 12.8 MB
    __fp16* LtT          = (__fp16*)p;  p += (size_t)FEAT * 384 * 2;       // 98 KB
    __fp16* Wb           = (__fp16*)p;  p += (size_t)FEAT * FEAT * 2;      // 32 KB
    float4* pk           = (float4*)p;  p += (size_t)N_NODES * 32;         // 1.6 MB
    int*   sord_p        = (int*)p;     p += (size_t)E_EDGES * 4;          // 3.2 MB
    int2*  bbuf          = (int2*)p;    p += (size_t)NBUK * BCAP * 8;      // 8.0 MB
    int*   cnt           = (int*)p;     p += 200064;
    float* sbuf          = (float*)p;   p += 1024;
    int*   gcur          = (int*)p;     p += 1024;   // memset covers cnt+sbuf+gcur
    int*   rowptr        = (int*)p;     p += 200064;
    int*   cursor        = (int*)p;     p += 200064;
    int*   bsum          = (int*)p;     p += 256;
    int*   boff          = (int*)p;     p += 256;

    hipMemsetAsync(cnt, 0, 200064 + 1024 + 1024, stream);

    const int NWB = (N_NODES * 64) / 256;         // 12500
    const int MB  = (N_NODES + 63) / 64;          // 782
    const int AB  = (E_EDGES + 2047) / 2048;      // 391

    wprep<<<FEAT, FEAT, 0, stream>>>(mlp_w, linear, Wb, LtT);
    g_cast<<<NWB, 256, 0, stream>>>(feature, coords, attW, fh, pk);

    bucketA<<<AB, 256, 0, stream>>>(src, dst, order, cnt, gcur, bbuf);
    scan1<<<NB1, 256, 0, stream>>>(cnt, rowptr, bsum);
    scan2<<<1, 64, 0, stream>>>(bsum, boff, rowptr);
    scan3<<<(N_NODES + 255) / 256, 256, 0, stream>>>(rowptr, cursor, boff);
    bucketB<<<NBUK * 8, 256, 0, stream>>>(gcur, bbuf, cursor, sord_p);

    segagg<<<NWB, 256, 0, stream>>>(pk, sord_p, rowptr, fh, agg);

    gemm1<<<MB, 256, 0, stream>>>(agg, LtT, hbuf, N_NODES);
    gemm2<<<MB, 256, 0, stream>>>(hbuf, Wb, out, N_NODES, mlp_b, sbuf);
    normalize<<<(N_NODES * 32) / 256, 256, 0, stream>>>(out, sbuf, gamma, beta);
}

// Round 11
// 211.778 us; speedup vs baseline: 1.0432x; 1.0432x over previous
//
#include <hip/hip_runtime.h>

#define N_NODES 50000
#define E_EDGES 800000
#define FEAT    128
#define KORD    3
#define BN_EPS  1e-5f
#define NB1     49          // ceil(50000/1024) scan blocks
#define NBUK    49          // coarse buckets (dst >> 10)
#define BCAP    20480       // bucket capacity

typedef __fp16 f16x2 __attribute__((ext_vector_type(2)));
typedef __fp16 f16x8 __attribute__((ext_vector_type(8)));
typedef __attribute__((ext_vector_type(4))) float f32x4;

__device__ __forceinline__ unsigned h2u(f16x2 h) { union { f16x2 h; unsigned u; } c; c.h = h; return c.u; }
__device__ __forceinline__ f16x2 u2h(unsigned u) { union { unsigned u; f16x2 h; } c; c.u = u; return c.h; }

// ---- weights prep (f16): Wb[o][i]=W[o][i];  LtT[o][k*128+i]=L[k][i][o] ----
__global__ void wprep(const float* __restrict__ W, const float* __restrict__ L,
                      __fp16* __restrict__ Wb, __fp16* __restrict__ LtT) {
    const int o = blockIdx.x;      // 128
    const int i = threadIdx.x;     // 128
    Wb[o * FEAT + i] = (__fp16)W[o * FEAT + i];
    #pragma unroll
    for (int k = 0; k < KORD; ++k)
        LtT[(size_t)o * 384 + k * FEAT + i] = (__fp16)L[((size_t)k * FEAT + i) * FEAT + o];
}

// ---- per node: feature->f16, and pack {coords, g=attW@f} into 2 float4 ----
__global__ void g_cast(const float* __restrict__ feat,
                       const float* __restrict__ coords,
                       const float* __restrict__ attW,
                       __fp16* __restrict__ fh,
                       float4* __restrict__ pk) {
    const int node = (blockIdx.x * blockDim.x + threadIdx.x) >> 6;
    const int lane = threadIdx.x & 63;
    if (node >= N_NODES) return;
    const float2 f = *(const float2*)(feat + (size_t)node * FEAT + lane * 2);
    *(f16x2*)(fh + (size_t)node * FEAT + lane * 2) = __builtin_amdgcn_cvt_pkrtz(f.x, f.y);
    float gg[3];
    #pragma unroll
    for (int j = 0; j < 3; ++j) {
        float p = f.x * attW[j * FEAT + lane * 2] + f.y * attW[j * FEAT + lane * 2 + 1];
        #pragma unroll
        for (int off = 32; off; off >>= 1) p += __shfl_xor(p, off);
        gg[j] = p;
    }
    if (lane == 0) {
        const float c0 = coords[node * 3 + 0], c1 = coords[node * 3 + 1], c2 = coords[node * 3 + 2];
        pk[2 * node]     = make_float4(c0, c1, c2, gg[0]);
        pk[2 * node + 1] = make_float4(gg[1], gg[2], 0.f, 0.f);
    }
}

// ============ CSR build ============
__global__ __launch_bounds__(256)
void bucketA(const int* __restrict__ src, const int* __restrict__ dst,
             const int* __restrict__ order,
             int* __restrict__ cnt, int* __restrict__ gcur, int2* __restrict__ bbuf) {
    __shared__ int lcnt[NBUK];
    __shared__ int lbase[NBUK];
    const int tid = threadIdx.x;
    if (tid < NBUK) lcnt[tid] = 0;
    __syncthreads();
    const int e0 = blockIdx.x * 2048;
    int b[8], r[8], so[8], dd[8];
    #pragma unroll
    for (int i = 0; i < 8; ++i) {
        const int e = e0 + i * 256 + tid;
        if (e < E_EDGES) {
            dd[i] = dst[e];
            so[i] = (order[e] << 16) | src[e];
            b[i] = dd[i] >> 10;
            r[i] = atomicAdd(&lcnt[b[i]], 1);
            atomicAdd(cnt + dd[i], 1);
        } else b[i] = -1;
    }
    __syncthreads();
    if (tid < NBUK) lbase[tid] = atomicAdd(&gcur[tid], lcnt[tid]);
    __syncthreads();
    #pragma unroll
    for (int i = 0; i < 8; ++i)
        if (b[i] >= 0)
            bbuf[(size_t)b[i] * BCAP + lbase[b[i]] + r[i]] = make_int2(so[i], dd[i]);
}

__global__ __launch_bounds__(256)
void scan1(const int* __restrict__ cnt, int* __restrict__ rowptr, int* __restrict__ bsum) {
    __shared__ int lds[256];
    const int b = blockIdx.x, t = threadIdx.x;
    const int base = b * 1024 + t * 4;
    int v[4];
    #pragma unroll
    for (int i = 0; i < 4; ++i) v[i] = (base + i < N_NODES) ? cnt[base + i] : 0;
    lds[t] = v[0] + v[1] + v[2] + v[3];
    __syncthreads();
    for (int off = 1; off < 256; off <<= 1) {
        const int u = (t >= off) ? lds[t - off] : 0;
        __syncthreads();
        lds[t] += u;
        __syncthreads();
    }
    int excl = t ? lds[t - 1] : 0;
    if (t == 255) bsum[b] = lds[255];
    #pragma unroll
    for (int i = 0; i < 4; ++i) {
        if (base + i < N_NODES) rowptr[base + i] = excl;
        excl += v[i];
    }
}

__global__ void scan2(const int* __restrict__ bsum, int* __restrict__ boff,
                      int* __restrict__ rowptr) {
    const int lane = threadIdx.x;   // 64
    const int v = (lane < NB1) ? bsum[lane] : 0;
    int incl = v;
    #pragma unroll
    for (int off = 1; off < 64; off <<= 1) {
        const int u = __shfl_up(incl, off);
        if (lane >= off) incl += u;
    }
    if (lane < NB1) boff[lane] = incl - v;
    if (lane == 0) rowptr[N_NODES] = E_EDGES;
}

__global__ void scan3(int* __restrict__ rowptr, int* __restrict__ cursor,
                      const int* __restrict__ boff) {
    const int i = blockIdx.x * blockDim.x + threadIdx.x;
    if (i >= N_NODES) return;
    const int v = rowptr[i] + boff[i >> 10];
    rowptr[i] = v;
    cursor[i] = v;
}

__global__ void bucketB(const int* __restrict__ gcur, const int2* __restrict__ bbuf,
                        int* __restrict__ cursor, int* __restrict__ sord_p) {
    const int b = blockIdx.x >> 3;
    const int seg = blockIdx.x & 7;
    const int n = gcur[b];
    const int lo = (int)((long)n * seg / 8), hi = (int)((long)n * (seg + 1) / 8);
    for (int i = lo + (int)threadIdx.x; i < hi; i += 256) {
        const int2 ent = bbuf[(size_t)b * BCAP + i];
        const int pos = atomicAdd(cursor + ent.y, 1);
        sord_p[pos] = ent.x;
    }
}

// ---- fused edge-att + segment softmax + per-order gather-aggregate ----
__global__ void segagg(const float4* __restrict__ pk,
                       const int* __restrict__ sord_p,
                       const int* __restrict__ rowptr,
                       const __fp16* __restrict__ fh,
                       __fp16* __restrict__ agg) {
    __shared__ uint4 stash[4][64];
    const int node = (blockIdx.x * blockDim.x + threadIdx.x) >> 6;
    const int lane = threadIdx.x & 63;
    const int wid  = threadIdx.x >> 6;
    if (node >= N_NODES) return;
    const int beg = rowptr[node], end = rowptr[node + 1];
    const float4 b0 = pk[2 * node];

    float att0 = -1e30f, inv0 = 0.f; int sol0 = 0;
    float m = -1e30f, s = 0.f;
    int nch = 0;
    for (int cb = beg; cb < end; cb += 64, ++nch) {
        const int p = cb + lane;
        float a = -1e30f, iv = 0.f; int so = 0;
        if (p < end) {
            so = sord_p[p];
            const int sn = so & 0xFFFF;
            const float4 a0 = pk[2 * sn], a1 = pk[2 * sn + 1];
            const float dx = a0.x - b0.x, dy = a0.y - b0.y, dz = a0.z - b0.z;
            a = dx * a0.w + dy * a1.x + dz * a1.y;
            iv = 1.f / (dx * dx + dy * dy + dz * dz + 1.f);
        }
        if (nch == 0) { att0 = a; inv0 = iv; sol0 = so; }
        const float mn = fmaxf(m, a);
        s = s * __expf(m - mn) + ((p < end) ? __expf(a - mn) : 0.f);
        m = mn;
    }
    #pragma unroll
    for (int off = 32; off; off >>= 1) {
        const float mo = __shfl_xor(m, off), so_ = __shfl_xor(s, off);
        const float mn = fmaxf(m, mo);
        s = s * __expf(m - mn) + so_ * __expf(mo - mn);
        m = mn;
    }
    const float inv_s = s > 0.f ? 1.f / s : 0.f;

    const int half = lane >> 5;
    const int lsub = lane & 31;
    f16x2 acc00 = {0, 0}, acc01 = {0, 0};
    f16x2 acc10 = {0, 0}, acc11 = {0, 0};
    f16x2 acc20 = {0, 0}, acc21 = {0, 0};

    int ch = 0;
    for (int cb = beg; cb < end; cb += 64, ++ch) {
        const int p = cb + lane;
        float wl = 0.f; int so = 0;
        if (ch == 0) {
            wl = __expf(att0 - m) * inv_s * inv0;
            so = sol0;
        } else if (p < end) {
            so = sord_p[p];
            const int sn = so & 0xFFFF;
            const float4 a0 = pk[2 * sn], a1 = pk[2 * sn + 1];
            const float dx = a0.x - b0.x, dy = a0.y - b0.y, dz = a0.z - b0.z;
            const float a = dx * a0.w + dy * a1.x + dz * a1.y;
            wl = __expf(a - m) * inv_s / (dx * dx + dy * dy + dz * dz + 1.f);
        }
        const int k = so >> 16;
        const __fp16 wh = (__fp16)wl;
        f16x2 w2; w2.x = wh; w2.y = wh;
        const unsigned uw = h2u(w2);
        stash[wid][lane] = make_uint4(k == 0 ? uw : 0u, k == 1 ? uw : 0u,
                                      k == 2 ? uw : 0u, (unsigned)(so & 0xFFFF));
        const int ne = min(64, end - cb);
        const uint4* st = stash[wid];
        for (int t = 0; t < ne; t += 2) {
            const uint4 e = st[t + half];
            const uint2 v = *(const uint2*)((const char*)fh + ((size_t)e.w << 8) + lsub * 8);
            const f16x2 va = u2h(v.x), vb = u2h(v.y);
            acc00 = __builtin_elementwise_fma(va, u2h(e.x), acc00);
            acc01 = __builtin_elementwise_fma(vb, u2h(e.x), acc01);
            acc10 = __builtin_elementwise_fma(va, u2h(e.y), acc10);
            acc11 = __builtin_elementwise_fma(vb, u2h(e.y), acc11);
            acc20 = __builtin_elementwise_fma(va, u2h(e.z), acc20);
            acc21 = __builtin_elementwise_fma(vb, u2h(e.z), acc21);
        }
    }
    acc00 = acc00 + u2h(__shfl_xor((int)h2u(acc00), 32));
    acc01 = acc01 + u2h(__shfl_xor((int)h2u(acc01), 32));
    acc10 = acc10 + u2h(__shfl_xor((int)h2u(acc10), 32));
    acc11 = acc11 + u2h(__shfl_xor((int)h2u(acc11), 32));
    acc20 = acc20 + u2h(__shfl_xor((int)h2u(acc20), 32));
    acc21 = acc21 + u2h(__shfl_xor((int)h2u(acc21), 32));
    if (lane < 32) {
        __fp16* row = agg + (size_t)node * 384 + lsub * 4;
        *(uint2*)(row)       = make_uint2(h2u(acc00), h2u(acc01));
        *(uint2*)(row + 128) = make_uint2(h2u(acc10), h2u(acc11));
        *(uint2*)(row + 256) = make_uint2(h2u(acc20), h2u(acc21));
    }
}

// ============================================================================
// fused64: y = relu((agg @ LtT^T) @ Wb^T + b) + BN stats, 64-row tile.
// 48KB LDS (As/h 16KB | Bs 32KB), 782 blocks -> 3 blocks/CU.
// h re-stage: f16 2B writes XOR-swizzled by (row&7)<<4 -> only 2-way (free);
// reads use the same XOR on 16B-aligned chunks (consistent involution).
// ============================================================================
__global__ __launch_bounds__(256)
void fused64(const __fp16* __restrict__ agg, const __fp16* __restrict__ LtT,
             const __fp16* __restrict__ Wb, float* __restrict__ out, int M,
             const float* __restrict__ bias, float* __restrict__ sbuf) {
    __shared__ char smem[49152];
    char* As = smem;            // 64 x 256B   (A-chunk, later h-f16)
    char* Bs = smem + 16384;    // 128 x 256B  (B-chunk)
    const int m0 = blockIdx.x * 64;
    const int tid = threadIdx.x;
    const int wave = tid >> 6, lane = tid & 63;
    const int wm0 = wave * 16;
    const int lrow = lane & 15;
    const int kslot = (lane >> 4) << 4;
    const int swz = (lrow & 7) << 4;

    f32x4 acc[8];
    #pragma unroll
    for (int b = 0; b < 8; ++b) acc[b] = (f32x4){0.f, 0.f, 0.f, 0.f};

    // ---- stage 1: h = agg @ LtT^T, K=384 in three 128-chunks ----
    for (int kc = 0; kc < 3; ++kc) {
        __syncthreads();
        #pragma unroll
        for (int p = tid; p < 1024; p += 256) {
            const int row = p >> 4, c = p & 15;
            const int off = (row << 8) + ((c << 4) ^ ((row & 7) << 4));
            float4 v = make_float4(0.f, 0.f, 0.f, 0.f);
            if (m0 + row < M)
                v = *(const float4*)(agg + (size_t)(m0 + row) * 384 + kc * 128 + c * 8);
            *(float4*)(As + off) = v;
        }
        #pragma unroll
        for (int p = tid; p < 2048; p += 256) {
            const int row = p >> 4, c = p & 15;
            const int off = (row << 8) + ((c << 4) ^ ((row & 7) << 4));
            *(float4*)(Bs + off) = *(const float4*)(LtT + (size_t)row * 384 + kc * 128 + c * 8);
        }
        __syncthreads();
        f16x8 afr[4];
        #pragma unroll
        for (int ks = 0; ks < 4; ++ks)
            afr[ks] = *(const f16x8*)(As + ((wm0 + lrow) << 8) + (((ks << 6) + kslot) ^ swz));
        #pragma unroll
        for (int nf = 0; nf < 8; ++nf) {
            #pragma unroll
            for (int ks = 0; ks < 4; ++ks) {
                f16x8 bfr = *(const f16x8*)(Bs + ((nf * 16 + lrow) << 8) + (((ks << 6) + kslot) ^ swz));
                acc[nf] = __builtin_amdgcn_mfma_f32_16x16x32_f16(afr[ks], bfr, acc[nf], 0, 0, 0);
            }
        }
    }

    // ---- re-stage h as f16 into As (swizzled, conflict-free) + stage Wb ----
    __syncthreads();
    #pragma unroll
    for (int nf = 0; nf < 8; ++nf)
        #pragma unroll
        for (int rg = 0; rg < 4; ++rg) {
            const int row = wm0 + (lane >> 4) * 4 + rg;          // 0..63
            const int off = (row << 8) + ((((nf * 16 + lrow) * 2)) ^ ((row & 7) << 4));
            *(__fp16*)(As + off) = (__fp16)acc[nf][rg];
        }
    #pragma unroll
    for (int p = tid; p < 2048; p += 256) {
        const int row = p >> 4, c = p & 15;
        const int off = (row << 8) + ((c << 4) ^ ((row & 7) << 4));
        *(float4*)(Bs + off) = *(const float4*)(Wb + (size_t)row * FEAT + c * 8);
    }
    __syncthreads();

    // ---- stage 2: y = h @ Wb^T, K=128 ----
    f32x4 acc2[8];
    #pragma unroll
    for (int b = 0; b < 8; ++b) acc2[b] = (f32x4){0.f, 0.f, 0.f, 0.f};
    f16x8 afr2[4];
    #pragma unroll
    for (int ks = 0; ks < 4; ++ks)
        afr2[ks] = *(const f16x8*)(As + ((wm0 + lrow) << 8) + (((ks << 6) + kslot) ^ swz));
    #pragma unroll
    for (int nf = 0; nf < 8; ++nf) {
        #pragma unroll
        for (int ks = 0; ks < 4; ++ks) {
            f16x8 bfr = *(const f16x8*)(Bs + ((nf * 16 + lrow) << 8) + (((ks << 6) + kslot) ^ swz));
            acc2[nf] = __builtin_amdgcn_mfma_f32_16x16x32_f16(afr2[ks], bfr, acc2[nf], 0, 0, 0);
        }
    }

    // ---- epilogue: bias + ReLU + store f32 + BN column stats ----
    float s[8], s2[8], bv[8];
    #pragma unroll
    for (int nf = 0; nf < 8; ++nf) { s[nf] = 0.f; s2[nf] = 0.f; bv[nf] = bias[nf * 16 + lrow]; }
    #pragma unroll
    for (int nf = 0; nf < 8; ++nf)
        #pragma unroll
        for (int rg = 0; rg < 4; ++rg) {
            const int row = m0 + wm0 + (lane >> 4) * 4 + rg;
            if (row < M) {
                const float v = fmaxf(acc2[nf][rg] + bv[nf], 0.f);
                out[(size_t)row * FEAT + nf * 16 + lrow] = v;
                s[nf] += v;
                s2[nf] = fmaf(v, v, s2[nf]);
            }
        }
    #pragma unroll
    for (int nf = 0; nf < 8; ++nf) {
        s[nf]  += __shfl_xor(s[nf], 16);  s[nf]  += __shfl_xor(s[nf], 32);
        s2[nf] += __shfl_xor(s2[nf], 16); s2[nf] += __shfl_xor(s2[nf], 32);
    }
    __syncthreads();
    float* red = (float*)smem;                // [4][256]
    if (lane < 16) {
        #pragma unroll
        for (int nf = 0; nf < 8; ++nf) {
            red[wave * 256 + nf * 16 + lane]       = s[nf];
            red[wave * 256 + 128 + nf * 16 + lane] = s2[nf];
        }
    }
    __syncthreads();
    if (tid < 128) {
        const float ss = red[tid] + red[256 + tid] + red[512 + tid] + red[768 + tid];
        const float qq = red[128 + tid] + red[384 + tid] + red[640 + tid] + red[896 + tid];
        atomicAdd(sbuf + tid, ss);
        atomicAdd(sbuf + FEAT + tid, qq);
    }
}

// ---- BN normalize (each block derives scale/shift from sbuf) ----
__global__ void normalize(float* __restrict__ y, const float* __restrict__ sbuf,
                          const float* __restrict__ gamma, const float* __restrict__ beta) {
    __shared__ float sc_s[FEAT], sh_s[FEAT];
    const int t = threadIdx.x;
    if (t < FEAT) {
        const float mean = sbuf[t] / (float)N_NODES;
        const float var  = sbuf[FEAT + t] / (float)N_NODES - mean * mean;
        const float sc   = gamma[t] * rsqrtf(var + BN_EPS);
        sc_s[t] = sc;
        sh_s[t] = beta[t] - mean * sc;
    }
    __syncthreads();
    const int idx = blockIdx.x * blockDim.x + t;
    const int o4 = (idx & 31) * 4;
    float4 v = *(float4*)(y + (size_t)idx * 4);
    const float4 sc = *(const float4*)(sc_s + o4);
    const float4 sh = *(const float4*)(sh_s + o4);
    v.x = fmaf(v.x, sc.x, sh.x);
    v.y = fmaf(v.y, sc.y, sh.y);
    v.z = fmaf(v.z, sc.z, sh.z);
    v.w = fmaf(v.w, sc.w, sh.w);
    *(float4*)(y + (size_t)idx * 4) = v;
}

extern "C" void kernel_launch(void* const* d_in, const int* in_sizes, int n_in,
                              void* d_out, int out_size, void* d_ws, size_t ws_size,
                              hipStream_t stream) {
    const float* feature = (const float*)d_in[0];
    const float* coords  = (const float*)d_in[1];
    const int*   src     = (const int*)d_in[2];
    const int*   dst     = (const int*)d_in[3];
    const int*   order   = (const int*)d_in[4];
    const float* linear  = (const float*)d_in[5];
    const float* attW    = (const float*)d_in[6];
    const float* mlp_w   = (const float*)d_in[7];
    const float* mlp_b   = (const float*)d_in[8];
    const float* gamma   = (const float*)d_in[9];
    const float* beta    = (const float*)d_in[10];
    float* out = (float*)d_out;

    char* p = (char*)d_ws;
    __fp16* fh           = (__fp16*)p;  p += (size_t)N_NODES * FEAT * 2;   // 12.8 MB
    __fp16* agg          = (__fp16*)p;  p += (size_t)N_NODES * 384 * 2;    // 38.4 MB
    __fp16* LtT          = (__fp16*)p;  p += (size_t)FEAT * 384 * 2;       // 98 KB
    __fp16* Wb           = (__fp16*)p;  p += (size_t)FEAT * FEAT * 2;      // 32 KB
    float4* pk           = (float4*)p;  p += (size_t)N_NODES * 32;         // 1.6 MB
    int*   sord_p        = (int*)p;     p += (size_t)E_EDGES * 4;          // 3.2 MB
    int2*  bbuf          = (int2*)p;    p += (size_t)NBUK * BCAP * 8;      // 8.0 MB
    int*   cnt           = (int*)p;     p += 200064;
    float* sbuf          = (float*)p;   p += 1024;
    int*   gcur          = (int*)p;     p += 1024;   // memset covers cnt+sbuf+gcur
    int*   rowptr        = (int*)p;     p += 200064;
    int*   cursor        = (int*)p;     p += 200064;
    int*   bsum          = (int*)p;     p += 256;
    int*   boff          = (int*)p;     p += 256;

    hipMemsetAsync(cnt, 0, 200064 + 1024 + 1024, stream);

    const int NWB = (N_NODES * 64) / 256;         // 12500
    const int MB  = (N_NODES + 63) / 64;          // 782
    const int AB  = (E_EDGES + 2047) / 2048;      // 391

    wprep<<<FEAT, FEAT, 0, stream>>>(mlp_w, linear, Wb, LtT);
    g_cast<<<NWB, 256, 0, stream>>>(feature, coords, attW, fh, pk);

    bucketA<<<AB, 256, 0, stream>>>(src, dst, order, cnt, gcur, bbuf);
    scan1<<<NB1, 256, 0, stream>>>(cnt, rowptr, bsum);
    scan2<<<1, 64, 0, stream>>>(bsum, boff, rowptr);
    scan3<<<(N_NODES + 255) / 256, 256, 0, stream>>>(rowptr, cursor, boff);
    bucketB<<<NBUK * 8, 256, 0, stream>>>(gcur, bbuf, cursor, sord_p);

    segagg<<<NWB, 256, 0, stream>>>(pk, sord_p, rowptr, fh, agg);

    fused64<<<MB, 256, 0, stream>>>(agg, LtT, Wb, out, N_NODES, mlp_b, sbuf);
    normalize<<<(N_NODES * 32) / 256, 256, 0, stream>>>(out, sbuf, gamma, beta);
}

// Round 12
// 201.944 us; speedup vs baseline: 1.0940x; 1.0487x over previous
//
#include <hip/hip_runtime.h>

#define N_NODES 50000
#define E_EDGES 800000
#define FEAT    128
#define KORD    3
#define BN_EPS  1e-5f
#define NB1     49          // ceil(50000/1024) scan blocks
#define NBUK    49          // coarse buckets (dst >> 10)
#define BCAP    20480       // bucket capacity
#define NSHARD  16          // BN-stats atomic shards

typedef __fp16 f16x2 __attribute__((ext_vector_type(2)));
typedef __fp16 f16x8 __attribute__((ext_vector_type(8)));
typedef __attribute__((ext_vector_type(4))) float f32x4;

__device__ __forceinline__ unsigned h2u(f16x2 h) { union { f16x2 h; unsigned u; } c; c.h = h; return c.u; }
__device__ __forceinline__ f16x2 u2h(unsigned u) { union { unsigned u; f16x2 h; } c; c.u = u; return c.h; }

// ---- weights prep (f16): Wb[o][i]=W[o][i];  LtT[o][k*128+i]=L[k][i][o] ----
__global__ void wprep(const float* __restrict__ W, const float* __restrict__ L,
                      __fp16* __restrict__ Wb, __fp16* __restrict__ LtT) {
    const int o = blockIdx.x;      // 128
    const int i = threadIdx.x;     // 128
    Wb[o * FEAT + i] = (__fp16)W[o * FEAT + i];
    #pragma unroll
    for (int k = 0; k < KORD; ++k)
        LtT[(size_t)o * 384 + k * FEAT + i] = (__fp16)L[((size_t)k * FEAT + i) * FEAT + o];
}

// ---- per node: feature->f16, and pack {coords, g=attW@f} into 2 float4 ----
__global__ void g_cast(const float* __restrict__ feat,
                       const float* __restrict__ coords,
                       const float* __restrict__ attW,
                       __fp16* __restrict__ fh,
                       float4* __restrict__ pk) {
    const int node = (blockIdx.x * blockDim.x + threadIdx.x) >> 6;
    const int lane = threadIdx.x & 63;
    if (node >= N_NODES) return;
    const float2 f = *(const float2*)(feat + (size_t)node * FEAT + lane * 2);
    *(f16x2*)(fh + (size_t)node * FEAT + lane * 2) = __builtin_amdgcn_cvt_pkrtz(f.x, f.y);
    float gg[3];
    #pragma unroll
    for (int j = 0; j < 3; ++j) {
        float p = f.x * attW[j * FEAT + lane * 2] + f.y * attW[j * FEAT + lane * 2 + 1];
        #pragma unroll
        for (int off = 32; off; off >>= 1) p += __shfl_xor(p, off);
        gg[j] = p;
    }
    if (lane == 0) {
        const float c0 = coords[node * 3 + 0], c1 = coords[node * 3 + 1], c2 = coords[node * 3 + 2];
        pk[2 * node]     = make_float4(c0, c1, c2, gg[0]);
        pk[2 * node + 1] = make_float4(gg[1], gg[2], 0.f, 0.f);
    }
}

// ============ CSR build ============
__global__ __launch_bounds__(256)
void bucketA(const int* __restrict__ src, const int* __restrict__ dst,
             const int* __restrict__ order,
             int* __restrict__ cnt, int* __restrict__ gcur, int2* __restrict__ bbuf) {
    __shared__ int lcnt[NBUK];
    __shared__ int lbase[NBUK];
    const int tid = threadIdx.x;
    if (tid < NBUK) lcnt[tid] = 0;
    __syncthreads();
    const int e0 = blockIdx.x * 2048;
    int b[8], r[8], so[8], dd[8];
    #pragma unroll
    for (int i = 0; i < 8; ++i) {
        const int e = e0 + i * 256 + tid;
        if (e < E_EDGES) {
            dd[i] = dst[e];
            so[i] = (order[e] << 16) | src[e];
            b[i] = dd[i] >> 10;
            r[i] = atomicAdd(&lcnt[b[i]], 1);
            atomicAdd(cnt + dd[i], 1);
        } else b[i] = -1;
    }
    __syncthreads();
    if (tid < NBUK) lbase[tid] = atomicAdd(&gcur[tid], lcnt[tid]);
    __syncthreads();
    #pragma unroll
    for (int i = 0; i < 8; ++i)
        if (b[i] >= 0)
            bbuf[(size_t)b[i] * BCAP + lbase[b[i]] + r[i]] = make_int2(so[i], dd[i]);
}

__global__ __launch_bounds__(256)
void scan1(const int* __restrict__ cnt, int* __restrict__ rowptr, int* __restrict__ bsum) {
    __shared__ int lds[256];
    const int b = blockIdx.x, t = threadIdx.x;
    const int base = b * 1024 + t * 4;
    int v[4];
    #pragma unroll
    for (int i = 0; i < 4; ++i) v[i] = (base + i < N_NODES) ? cnt[base + i] : 0;
    lds[t] = v[0] + v[1] + v[2] + v[3];
    __syncthreads();
    for (int off = 1; off < 256; off <<= 1) {
        const int u = (t >= off) ? lds[t - off] : 0;
        __syncthreads();
        lds[t] += u;
        __syncthreads();
    }
    int excl = t ? lds[t - 1] : 0;
    if (t == 255) bsum[b] = lds[255];
    #pragma unroll
    for (int i = 0; i < 4; ++i) {
        if (base + i < N_NODES) rowptr[base + i] = excl;
        excl += v[i];
    }
}

__global__ void scan2(const int* __restrict__ bsum, int* __restrict__ boff,
                      int* __restrict__ rowptr) {
    const int lane = threadIdx.x;   // 64
    const int v = (lane < NB1) ? bsum[lane] : 0;
    int incl = v;
    #pragma unroll
    for (int off = 1; off < 64; off <<= 1) {
        const int u = __shfl_up(incl, off);
        if (lane >= off) incl += u;
    }
    if (lane < NB1) boff[lane] = incl - v;
    if (lane == 0) rowptr[N_NODES] = E_EDGES;
}

__global__ void scan3(int* __restrict__ rowptr, int* __restrict__ cursor,
                      const int* __restrict__ boff) {
    const int i = blockIdx.x * blockDim.x + threadIdx.x;
    if (i >= N_NODES) return;
    const int v = rowptr[i] + boff[i >> 10];
    rowptr[i] = v;
    cursor[i] = v;
}

__global__ void bucketB(const int* __restrict__ gcur, const int2* __restrict__ bbuf,
                        int* __restrict__ cursor, int* __restrict__ sord_p) {
    const int b = blockIdx.x >> 3;
    const int seg = blockIdx.x & 7;
    const int n = gcur[b];
    const int lo = (int)((long)n * seg / 8), hi = (int)((long)n * (seg + 1) / 8);
    for (int i = lo + (int)threadIdx.x; i < hi; i += 256) {
        const int2 ent = bbuf[(size_t)b * BCAP + i];
        const int pos = atomicAdd(cursor + ent.y, 1);
        sord_p[pos] = ent.x;
    }
}

// ---- fused edge-att + segment softmax + per-order gather-aggregate ----
__global__ void segagg(const float4* __restrict__ pk,
                       const int* __restrict__ sord_p,
                       const int* __restrict__ rowptr,
                       const __fp16* __restrict__ fh,
                       __fp16* __restrict__ agg) {
    __shared__ uint4 stash[4][64];
    const int node = (blockIdx.x * blockDim.x + threadIdx.x) >> 6;
    const int lane = threadIdx.x & 63;
    const int wid  = threadIdx.x >> 6;
    if (node >= N_NODES) return;
    const int beg = rowptr[node], end = rowptr[node + 1];
    const float4 b0 = pk[2 * node];

    float att0 = -1e30f, inv0 = 0.f; int sol0 = 0;
    float m = -1e30f, s = 0.f;
    int nch = 0;
    for (int cb = beg; cb < end; cb += 64, ++nch) {
        const int p = cb + lane;
        float a = -1e30f, iv = 0.f; int so = 0;
        if (p < end) {
            so = sord_p[p];
            const int sn = so & 0xFFFF;
            const float4 a0 = pk[2 * sn], a1 = pk[2 * sn + 1];
            const float dx = a0.x - b0.x, dy = a0.y - b0.y, dz = a0.z - b0.z;
            a = dx * a0.w + dy * a1.x + dz * a1.y;
            iv = 1.f / (dx * dx + dy * dy + dz * dz + 1.f);
        }
        if (nch == 0) { att0 = a; inv0 = iv; sol0 = so; }
        const float mn = fmaxf(m, a);
        s = s * __expf(m - mn) + ((p < end) ? __expf(a - mn) : 0.f);
        m = mn;
    }
    #pragma unroll
    for (int off = 32; off; off >>= 1) {
        const float mo = __shfl_xor(m, off), so_ = __shfl_xor(s, off);
        const float mn = fmaxf(m, mo);
        s = s * __expf(m - mn) + so_ * __expf(mo - mn);
        m = mn;
    }
    const float inv_s = s > 0.f ? 1.f / s : 0.f;

    const int half = lane >> 5;
    const int lsub = lane & 31;
    f16x2 acc00 = {0, 0}, acc01 = {0, 0};
    f16x2 acc10 = {0, 0}, acc11 = {0, 0};
    f16x2 acc20 = {0, 0}, acc21 = {0, 0};

    int ch = 0;
    for (int cb = beg; cb < end; cb += 64, ++ch) {
        const int p = cb + lane;
        float wl = 0.f; int so = 0;
        if (ch == 0) {
            wl = __expf(att0 - m) * inv_s * inv0;
            so = sol0;
        } else if (p < end) {
            so = sord_p[p];
            const int sn = so & 0xFFFF;
            const float4 a0 = pk[2 * sn], a1 = pk[2 * sn + 1];
            const float dx = a0.x - b0.x, dy = a0.y - b0.y, dz = a0.z - b0.z;
            const float a = dx * a0.w + dy * a1.x + dz * a1.y;
            wl = __expf(a - m) * inv_s / (dx * dx + dy * dy + dz * dz + 1.f);
        }
        const int k = so >> 16;
        const __fp16 wh = (__fp16)wl;
        f16x2 w2; w2.x = wh; w2.y = wh;
        const unsigned uw = h2u(w2);
        stash[wid][lane] = make_uint4(k == 0 ? uw : 0u, k == 1 ? uw : 0u,
                                      k == 2 ? uw : 0u, (unsigned)(so & 0xFFFF));
        const int ne = min(64, end - cb);
        const uint4* st = stash[wid];
        for (int t = 0; t < ne; t += 2) {
            const uint4 e = st[t + half];
            const uint2 v = *(const uint2*)((const char*)fh + ((size_t)e.w << 8) + lsub * 8);
            const f16x2 va = u2h(v.x), vb = u2h(v.y);
            acc00 = __builtin_elementwise_fma(va, u2h(e.x), acc00);
            acc01 = __builtin_elementwise_fma(vb, u2h(e.x), acc01);
            acc10 = __builtin_elementwise_fma(va, u2h(e.y), acc10);
            acc11 = __builtin_elementwise_fma(vb, u2h(e.y), acc11);
            acc20 = __builtin_elementwise_fma(va, u2h(e.z), acc20);
            acc21 = __builtin_elementwise_fma(vb, u2h(e.z), acc21);
        }
    }
    acc00 = acc00 + u2h(__shfl_xor((int)h2u(acc00), 32));
    acc01 = acc01 + u2h(__shfl_xor((int)h2u(acc01), 32));
    acc10 = acc10 + u2h(__shfl_xor((int)h2u(acc10), 32));
    acc11 = acc11 + u2h(__shfl_xor((int)h2u(acc11), 32));
    acc20 = acc20 + u2h(__shfl_xor((int)h2u(acc20), 32));
    acc21 = acc21 + u2h(__shfl_xor((int)h2u(acc21), 32));
    if (lane < 32) {
        __fp16* row = agg + (size_t)node * 384 + lsub * 4;
        *(uint2*)(row)       = make_uint2(h2u(acc00), h2u(acc01));
        *(uint2*)(row + 128) = make_uint2(h2u(acc10), h2u(acc11));
        *(uint2*)(row + 256) = make_uint2(h2u(acc20), h2u(acc21));
    }
}

// ============================================================================
// fused_w: y = relu((agg @ LtT^T) @ Wb^T + b) + BN stats.
// ONE WAVE per block, 32 rows, ZERO barriers: A and B fragments loaded
// DIRECTLY from global (row-major [.][k] is exactly the k-contiguous 16B/lane
// fragment layout of mfma_16x16x32_f16). h lives in per-wave-private LDS
// (in-order within wave). 1563 blocks, 12 waves/CU, fully latency-overlapped.
// ============================================================================
__global__ __launch_bounds__(64, 3)
void fused_w(const __fp16* __restrict__ agg, const __fp16* __restrict__ LtT,
             const __fp16* __restrict__ Wb, float* __restrict__ out,
             const float* __restrict__ bias, float* __restrict__ sbuf) {
    __shared__ char hlds[32 * 256];       // 8KB: h[32][128] f16, XOR-swizzled
    const int m0 = blockIdx.x * 32;
    const int lane = threadIdx.x;
    const int lrow = lane & 15;
    const int kg = lane >> 2 >> 2;        // lane>>4: 0..3

    f32x4 acc[2][8];
    #pragma unroll
    for (int a = 0; a < 2; ++a)
        #pragma unroll
        for (int b = 0; b < 8; ++b) acc[a][b] = (f32x4){0.f, 0.f, 0.f, 0.f};

    // ---- stage 1: h = agg @ LtT^T, K=384, fragments direct from global ----
    #pragma unroll
    for (int kc = 0; kc < 3; ++kc) {
        f16x8 afr[2][4];
        #pragma unroll
        for (int mf = 0; mf < 2; ++mf) {
            const int row = min(m0 + mf * 16 + lrow, N_NODES - 1);
            const __fp16* ap = agg + (size_t)row * 384 + kc * 128 + kg * 8;
            #pragma unroll
            for (int ks = 0; ks < 4; ++ks)
                afr[mf][ks] = *(const f16x8*)(ap + ks * 32);
        }
        #pragma unroll
        for (int nf = 0; nf < 8; ++nf) {
            const __fp16* bp = LtT + (size_t)(nf * 16 + lrow) * 384 + kc * 128 + kg * 8;
            #pragma unroll
            for (int ks = 0; ks < 4; ++ks) {
                const f16x8 bfr = *(const f16x8*)(bp + ks * 32);
                acc[0][nf] = __builtin_amdgcn_mfma_f32_16x16x32_f16(afr[0][ks], bfr, acc[0][nf], 0, 0, 0);
                acc[1][nf] = __builtin_amdgcn_mfma_f32_16x16x32_f16(afr[1][ks], bfr, acc[1][nf], 0, 0, 0);
            }
        }
    }

    // ---- re-stage h into per-wave LDS (f16, swizzled; no barrier needed) ----
    #pragma unroll
    for (int mf = 0; mf < 2; ++mf)
        #pragma unroll
        for (int nf = 0; nf < 8; ++nf)
            #pragma unroll
            for (int rg = 0; rg < 4; ++rg) {
                const int row = mf * 16 + kg * 4 + rg;            // 0..31
                const int off = (row << 8) + (((nf * 16 + lrow) * 2) ^ ((row & 7) << 4));
                *(__fp16*)(hlds + off) = (__fp16)acc[mf][nf][rg];
            }

    // ---- stage 2: y = h @ Wb^T, K=128; A from LDS, B direct from global ----
    f32x4 acc2[2][8];
    #pragma unroll
    for (int a = 0; a < 2; ++a)
        #pragma unroll
        for (int b = 0; b < 8; ++b) acc2[a][b] = (f32x4){0.f, 0.f, 0.f, 0.f};
    f16x8 afr2[2][4];
    #pragma unroll
    for (int mf = 0; mf < 2; ++mf) {
        const int row = mf * 16 + lrow;
        #pragma unroll
        for (int ks = 0; ks < 4; ++ks)
            afr2[mf][ks] = *(const f16x8*)(hlds + (row << 8) +
                                           (((ks * 64) + kg * 16) ^ ((row & 7) << 4)));
    }
    #pragma unroll
    for (int nf = 0; nf < 8; ++nf) {
        const __fp16* bp = Wb + (size_t)(nf * 16 + lrow) * FEAT + kg * 8;
        #pragma unroll
        for (int ks = 0; ks < 4; ++ks) {
            const f16x8 bfr = *(const f16x8*)(bp + ks * 32);
            acc2[0][nf] = __builtin_amdgcn_mfma_f32_16x16x32_f16(afr2[0][ks], bfr, acc2[0][nf], 0, 0, 0);
            acc2[1][nf] = __builtin_amdgcn_mfma_f32_16x16x32_f16(afr2[1][ks], bfr, acc2[1][nf], 0, 0, 0);
        }
    }

    // ---- epilogue: bias + ReLU + store f32 + sharded BN column stats ----
    float s[8], s2[8], bv[8];
    #pragma unroll
    for (int nf = 0; nf < 8; ++nf) { s[nf] = 0.f; s2[nf] = 0.f; bv[nf] = bias[nf * 16 + lrow]; }
    #pragma unroll
    for (int mf = 0; mf < 2; ++mf)
        #pragma unroll
        for (int nf = 0; nf < 8; ++nf)
            #pragma unroll
            for (int rg = 0; rg < 4; ++rg) {
                const int row = m0 + mf * 16 + kg * 4 + rg;
                if (row < N_NODES) {
                    const float v = fmaxf(acc2[mf][nf][rg] + bv[nf], 0.f);
                    out[(size_t)row * FEAT + nf * 16 + lrow] = v;
                    s[nf] += v;
                    s2[nf] = fmaf(v, v, s2[nf]);
                }
            }
    #pragma unroll
    for (int nf = 0; nf < 8; ++nf) {
        s[nf]  += __shfl_xor(s[nf], 16);  s[nf]  += __shfl_xor(s[nf], 32);
        s2[nf] += __shfl_xor(s2[nf], 16); s2[nf] += __shfl_xor(s2[nf], 32);
    }
    if (lane < 16) {
        float* sb = sbuf + (blockIdx.x & (NSHARD - 1)) * 256;
        #pragma unroll
        for (int nf = 0; nf < 8; ++nf) {
            atomicAdd(sb + nf * 16 + lrow, s[nf]);
            atomicAdd(sb + 128 + nf * 16 + lrow, s2[nf]);
        }
    }
}

// ---- BN normalize (sums the 16 stat shards, derives scale/shift) ----
__global__ void normalize(float* __restrict__ y, const float* __restrict__ sbuf,
                          const float* __restrict__ gamma, const float* __restrict__ beta) {
    __shared__ float sc_s[FEAT], sh_s[FEAT];
    const int t = threadIdx.x;
    if (t < FEAT) {
        float ssum = 0.f, qsum = 0.f;
        #pragma unroll
        for (int sh = 0; sh < NSHARD; ++sh) {
            ssum += sbuf[sh * 256 + t];
            qsum += sbuf[sh * 256 + 128 + t];
        }
        const float mean = ssum / (float)N_NODES;
        const float var  = qsum / (float)N_NODES - mean * mean;
        const float sc   = gamma[t] * rsqrtf(var + BN_EPS);
        sc_s[t] = sc;
        sh_s[t] = beta[t] - mean * sc;
    }
    __syncthreads();
    const int idx = blockIdx.x * blockDim.x + t;
    const int o4 = (idx & 31) * 4;
    float4 v = *(float4*)(y + (size_t)idx * 4);
    const float4 sc = *(const float4*)(sc_s + o4);
    const float4 sh = *(const float4*)(sh_s + o4);
    v.x = fmaf(v.x, sc.x, sh.x);
    v.y = fmaf(v.y, sc.y, sh.y);
    v.z = fmaf(v.z, sc.z, sh.z);
    v.w = fmaf(v.w, sc.w, sh.w);
    *(float4*)(y + (size_t)idx * 4) = v;
}

extern "C" void kernel_launch(void* const* d_in, const int* in_sizes, int n_in,
                              void* d_out, int out_size, void* d_ws, size_t ws_size,
                              hipStream_t stream) {
    const float* feature = (const float*)d_in[0];
    const float* coords  = (const float*)d_in[1];
    const int*   src     = (const int*)d_in[2];
    const int*   dst     = (const int*)d_in[3];
    const int*   order   = (const int*)d_in[4];
    const float* linear  = (const float*)d_in[5];
    const float* attW    = (const float*)d_in[6];
    const float* mlp_w   = (const float*)d_in[7];
    const float* mlp_b   = (const float*)d_in[8];
    const float* gamma   = (const float*)d_in[9];
    const float* beta    = (const float*)d_in[10];
    float* out = (float*)d_out;

    char* p = (char*)d_ws;
    __fp16* fh           = (__fp16*)p;  p += (size_t)N_NODES * FEAT * 2;   // 12.8 MB
    __fp16* agg          = (__fp16*)p;  p += (size_t)N_NODES * 384 * 2;    // 38.4 MB
    __fp16* LtT          = (__fp16*)p;  p += (size_t)FEAT * 384 * 2;       // 98 KB
    __fp16* Wb           = (__fp16*)p;  p += (size_t)FEAT * FEAT * 2;      // 32 KB
    float4* pk           = (float4*)p;  p += (size_t)N_NODES * 32;         // 1.6 MB
    int*   sord_p        = (int*)p;     p += (size_t)E_EDGES * 4;          // 3.2 MB
    int2*  bbuf          = (int2*)p;    p += (size_t)NBUK * BCAP * 8;      // 8.0 MB
    int*   cnt           = (int*)p;     p += 200064;
    float* sbuf          = (float*)p;   p += NSHARD * 256 * 4;             // 16 KB
    int*   gcur          = (int*)p;     p += 1024;   // memset covers cnt+sbuf+gcur
    int*   rowptr        = (int*)p;     p += 200064;
    int*   cursor        = (int*)p;     p += 200064;
    int*   bsum          = (int*)p;     p += 256;
    int*   boff          = (int*)p;     p += 256;

    hipMemsetAsync(cnt, 0, 200064 + NSHARD * 256 * 4 + 1024, stream);

    const int NWB = (N_NODES * 64) / 256;         // 12500
    const int WB  = (N_NODES + 31) / 32;          // 1563 one-wave blocks
    const int AB  = (E_EDGES + 2047) / 2048;      // 391

    wprep<<<FEAT, FEAT, 0, stream>>>(mlp_w, linear, Wb, LtT);
    g_cast<<<NWB, 256, 0, stream>>>(feature, coords, attW, fh, pk);

    bucketA<<<AB, 256, 0, stream>>>(src, dst, order, cnt, gcur, bbuf);
    scan1<<<NB1, 256, 0, stream>>>(cnt, rowptr, bsum);
    scan2<<<1, 64, 0, stream>>>(bsum, boff, rowptr);
    scan3<<<(N_NODES + 255) / 256, 256, 0, stream>>>(rowptr, cursor, boff);
    bucketB<<<NBUK * 8, 256, 0, stream>>>(gcur, bbuf, cursor, sord_p);

    segagg<<<NWB, 256, 0, stream>>>(pk, sord_p, rowptr, fh, agg);

    fused_w<<<WB, 64, 0, stream>>>(agg, LtT, Wb, out, mlp_b, sbuf);
    normalize<<<(N_NODES * 32) / 256, 256, 0, stream>>>(out, sbuf, gamma, beta);
}

// Round 13
// 200.778 us; speedup vs baseline: 1.1004x; 1.0058x over previous
//
#include <hip/hip_runtime.h>

#define N_NODES 50000
#define E_EDGES 800000
#define FEAT    128
#define KORD    3
#define BN_EPS  1e-5f
#define NB1     49          // ceil(50000/1024) scan blocks
#define NBUK    49          // coarse buckets (dst >> 10)
#define BCAP    20480       // bucket capacity
#define NSHARD  16          // BN-stats atomic shards

typedef __fp16 f16x2 __attribute__((ext_vector_type(2)));
typedef __fp16 f16x8 __attribute__((ext_vector_type(8)));
typedef __attribute__((ext_vector_type(4))) float f32x4;

__device__ __forceinline__ unsigned h2u(f16x2 h) { union { f16x2 h; unsigned u; } c; c.h = h; return c.u; }
__device__ __forceinline__ f16x2 u2h(unsigned u) { union { unsigned u; f16x2 h; } c; c.u = u; return c.h; }

// ---- fold the two linear layers: GT[o][k*128+i] = sum_j L[k][i][j] * W[o][j]
__global__ void gprep(const float* __restrict__ W, const float* __restrict__ L,
                      __fp16* __restrict__ GT) {
    __shared__ float wrow[FEAT];
    const int o = blockIdx.x;      // 128
    const int i = threadIdx.x;     // 128
    wrow[i] = W[o * FEAT + i];
    __syncthreads();
    #pragma unroll
    for (int k = 0; k < KORD; ++k) {
        const float* lp = L + ((size_t)k * FEAT + i) * FEAT;
        float acc = 0.f;
        #pragma unroll 8
        for (int j = 0; j < FEAT; ++j) acc = fmaf(lp[j], wrow[j], acc);
        GT[(size_t)o * 384 + k * FEAT + i] = (__fp16)acc;
    }
}

// ---- per node: feature->f16, and pack {coords, g=attW@f} into 2 float4 ----
__global__ void g_cast(const float* __restrict__ feat,
                       const float* __restrict__ coords,
                       const float* __restrict__ attW,
                       __fp16* __restrict__ fh,
                       float4* __restrict__ pk) {
    const int node = (blockIdx.x * blockDim.x + threadIdx.x) >> 6;
    const int lane = threadIdx.x & 63;
    if (node >= N_NODES) return;
    const float2 f = *(const float2*)(feat + (size_t)node * FEAT + lane * 2);
    *(f16x2*)(fh + (size_t)node * FEAT + lane * 2) = __builtin_amdgcn_cvt_pkrtz(f.x, f.y);
    float gg[3];
    #pragma unroll
    for (int j = 0; j < 3; ++j) {
        float p = f.x * attW[j * FEAT + lane * 2] + f.y * attW[j * FEAT + lane * 2 + 1];
        #pragma unroll
        for (int off = 32; off; off >>= 1) p += __shfl_xor(p, off);
        gg[j] = p;
    }
    if (lane == 0) {
        const float c0 = coords[node * 3 + 0], c1 = coords[node * 3 + 1], c2 = coords[node * 3 + 2];
        pk[2 * node]     = make_float4(c0, c1, c2, gg[0]);
        pk[2 * node + 1] = make_float4(gg[1], gg[2], 0.f, 0.f);
    }
}

// ============ CSR build ============
__global__ __launch_bounds__(256)
void bucketA(const int* __restrict__ src, const int* __restrict__ dst,
             const int* __restrict__ order,
             int* __restrict__ cnt, int* __restrict__ gcur, int2* __restrict__ bbuf) {
    __shared__ int lcnt[NBUK];
    __shared__ int lbase[NBUK];
    const int tid = threadIdx.x;
    if (tid < NBUK) lcnt[tid] = 0;
    __syncthreads();
    const int e0 = blockIdx.x * 2048;
    int b[8], r[8], so[8], dd[8];
    #pragma unroll
    for (int i = 0; i < 8; ++i) {
        const int e = e0 + i * 256 + tid;
        if (e < E_EDGES) {
            dd[i] = dst[e];
            so[i] = (order[e] << 16) | src[e];
            b[i] = dd[i] >> 10;
            r[i] = atomicAdd(&lcnt[b[i]], 1);
            atomicAdd(cnt + dd[i], 1);
        } else b[i] = -1;
    }
    __syncthreads();
    if (tid < NBUK) lbase[tid] = atomicAdd(&gcur[tid], lcnt[tid]);
    __syncthreads();
    #pragma unroll
    for (int i = 0; i < 8; ++i)
        if (b[i] >= 0)
            bbuf[(size_t)b[i] * BCAP + lbase[b[i]] + r[i]] = make_int2(so[i], dd[i]);
}

__global__ __launch_bounds__(256)
void scan1(const int* __restrict__ cnt, int* __restrict__ rowptr, int* __restrict__ bsum) {
    __shared__ int lds[256];
    const int b = blockIdx.x, t = threadIdx.x;
    const int base = b * 1024 + t * 4;
    int v[4];
    #pragma unroll
    for (int i = 0; i < 4; ++i) v[i] = (base + i < N_NODES) ? cnt[base + i] : 0;
    lds[t] = v[0] + v[1] + v[2] + v[3];
    __syncthreads();
    for (int off = 1; off < 256; off <<= 1) {
        const int u = (t >= off) ? lds[t - off] : 0;
        __syncthreads();
        lds[t] += u;
        __syncthreads();
    }
    int excl = t ? lds[t - 1] : 0;
    if (t == 255) bsum[b] = lds[255];
    #pragma unroll
    for (int i = 0; i < 4; ++i) {
        if (base + i < N_NODES) rowptr[base + i] = excl;
        excl += v[i];
    }
}

__global__ void scan2(const int* __restrict__ bsum, int* __restrict__ boff,
                      int* __restrict__ rowptr) {
    const int lane = threadIdx.x;   // 64
    const int v = (lane < NB1) ? bsum[lane] : 0;
    int incl = v;
    #pragma unroll
    for (int off = 1; off < 64; off <<= 1) {
        const int u = __shfl_up(incl, off);
        if (lane >= off) incl += u;
    }
    if (lane < NB1) boff[lane] = incl - v;
    if (lane == 0) rowptr[N_NODES] = E_EDGES;
}

__global__ void scan3(int* __restrict__ rowptr, int* __restrict__ cursor,
                      const int* __restrict__ boff) {
    const int i = blockIdx.x * blockDim.x + threadIdx.x;
    if (i >= N_NODES) return;
    const int v = rowptr[i] + boff[i >> 10];
    rowptr[i] = v;
    cursor[i] = v;
}

__global__ void bucketB(const int* __restrict__ gcur, const int2* __restrict__ bbuf,
                        int* __restrict__ cursor, int* __restrict__ sord_p) {
    const int b = blockIdx.x >> 3;
    const int seg = blockIdx.x & 7;
    const int n = gcur[b];
    const int lo = (int)((long)n * seg / 8), hi = (int)((long)n * (seg + 1) / 8);
    for (int i = lo + (int)threadIdx.x; i < hi; i += 256) {
        const int2 ent = bbuf[(size_t)b * BCAP + i];
        const int pos = atomicAdd(cursor + ent.y, 1);
        sord_p[pos] = ent.x;
    }
}

// ---- fused edge-att + segment softmax + per-order gather-aggregate ----
__global__ void segagg(const float4* __restrict__ pk,
                       const int* __restrict__ sord_p,
                       const int* __restrict__ rowptr,
                       const __fp16* __restrict__ fh,
                       __fp16* __restrict__ agg) {
    __shared__ uint4 stash[4][64];
    const int node = (blockIdx.x * blockDim.x + threadIdx.x) >> 6;
    const int lane = threadIdx.x & 63;
    const int wid  = threadIdx.x >> 6;
    if (node >= N_NODES) return;
    const int beg = rowptr[node], end = rowptr[node + 1];
    const float4 b0 = pk[2 * node];

    float att0 = -1e30f, inv0 = 0.f; int sol0 = 0;
    float m = -1e30f, s = 0.f;
    int nch = 0;
    for (int cb = beg; cb < end; cb += 64, ++nch) {
        const int p = cb + lane;
        float a = -1e30f, iv = 0.f; int so = 0;
        if (p < end) {
            so = sord_p[p];
            const int sn = so & 0xFFFF;
            const float4 a0 = pk[2 * sn], a1 = pk[2 * sn + 1];
            const float dx = a0.x - b0.x, dy = a0.y - b0.y, dz = a0.z - b0.z;
            a = dx * a0.w + dy * a1.x + dz * a1.y;
            iv = 1.f / (dx * dx + dy * dy + dz * dz + 1.f);
        }
        if (nch == 0) { att0 = a; inv0 = iv; sol0 = so; }
        const float mn = fmaxf(m, a);
        s = s * __expf(m - mn) + ((p < end) ? __expf(a - mn) : 0.f);
        m = mn;
    }
    #pragma unroll
    for (int off = 32; off; off >>= 1) {
        const float mo = __shfl_xor(m, off), so_ = __shfl_xor(s, off);
        const float mn = fmaxf(m, mo);
        s = s * __expf(m - mn) + so_ * __expf(mo - mn);
        m = mn;
    }
    const float inv_s = s > 0.f ? 1.f / s : 0.f;

    const int half = lane >> 5;
    const int lsub = lane & 31;
    f16x2 acc00 = {0, 0}, acc01 = {0, 0};
    f16x2 acc10 = {0, 0}, acc11 = {0, 0};
    f16x2 acc20 = {0, 0}, acc21 = {0, 0};

    int ch = 0;
    for (int cb = beg; cb < end; cb += 64, ++ch) {
        const int p = cb + lane;
        float wl = 0.f; int so = 0;
        if (ch == 0) {
            wl = __expf(att0 - m) * inv_s * inv0;
            so = sol0;
        } else if (p < end) {
            so = sord_p[p];
            const int sn = so & 0xFFFF;
            const float4 a0 = pk[2 * sn], a1 = pk[2 * sn + 1];
            const float dx = a0.x - b0.x, dy = a0.y - b0.y, dz = a0.z - b0.z;
            const float a = dx * a0.w + dy * a1.x + dz * a1.y;
            wl = __expf(a - m) * inv_s / (dx * dx + dy * dy + dz * dz + 1.f);
        }
        const int k = so >> 16;
        const __fp16 wh = (__fp16)wl;
        f16x2 w2; w2.x = wh; w2.y = wh;
        const unsigned uw = h2u(w2);
        stash[wid][lane] = make_uint4(k == 0 ? uw : 0u, k == 1 ? uw : 0u,
                                      k == 2 ? uw : 0u, (unsigned)(so & 0xFFFF));
        const int ne = min(64, end - cb);
        const uint4* st = stash[wid];
        for (int t = 0; t < ne; t += 2) {
            const uint4 e = st[t + half];
            const uint2 v = *(const uint2*)((const char*)fh + ((size_t)e.w << 8) + lsub * 8);
            const f16x2 va = u2h(v.x), vb = u2h(v.y);
            acc00 = __builtin_elementwise_fma(va, u2h(e.x), acc00);
            acc01 = __builtin_elementwise_fma(vb, u2h(e.x), acc01);
            acc10 = __builtin_elementwise_fma(va, u2h(e.y), acc10);
            acc11 = __builtin_elementwise_fma(vb, u2h(e.y), acc11);
            acc20 = __builtin_elementwise_fma(va, u2h(e.z), acc20);
            acc21 = __builtin_elementwise_fma(vb, u2h(e.z), acc21);
        }
    }
    acc00 = acc00 + u2h(__shfl_xor((int)h2u(acc00), 32));
    acc01 = acc01 + u2h(__shfl_xor((int)h2u(acc01), 32));
    acc10 = acc10 + u2h(__shfl_xor((int)h2u(acc10), 32));
    acc11 = acc11 + u2h(__shfl_xor((int)h2u(acc11), 32));
    acc20 = acc20 + u2h(__shfl_xor((int)h2u(acc20), 32));
    acc21 = acc21 + u2h(__shfl_xor((int)h2u(acc21), 32));
    if (lane < 32) {
        __fp16* row = agg + (size_t)node * 384 + lsub * 4;
        *(uint2*)(row)       = make_uint2(h2u(acc00), h2u(acc01));
        *(uint2*)(row + 128) = make_uint2(h2u(acc10), h2u(acc11));
        *(uint2*)(row + 256) = make_uint2(h2u(acc20), h2u(acc21));
    }
}

// ============================================================================
// mlp_gemm: y[m,o] = relu(sum_{ki<384} agg[m,ki]*GT[o,ki] + b[o]) + BN stats.
// Single K=384 stage (two linear layers pre-folded into GT by gprep).
// 64-row M-tile, 256 thr (4 waves x 16 rows), 48KB LDS -> 3 blocks/CU.
// ============================================================================
__global__ __launch_bounds__(256)
void mlp_gemm(const __fp16* __restrict__ agg, const __fp16* __restrict__ GT,
              float* __restrict__ out, int M,
              const float* __restrict__ bias, float* __restrict__ sbuf) {
    __shared__ char smem[49152];          // As[64][128] 16KB | Bs[128][128] 32KB
    char* As = smem;
    char* Bs = smem + 16384;
    const int m0 = blockIdx.x * 64;
    const int tid = threadIdx.x;
    const int wave = tid >> 6, lane = tid & 63;
    const int wm0 = wave * 16;
    const int lrow = lane & 15;
    const int kslot = (lane >> 4) << 4;
    const int swz = (lrow & 7) << 4;

    f32x4 acc[8];
    #pragma unroll
    for (int b = 0; b < 8; ++b) acc[b] = (f32x4){0.f, 0.f, 0.f, 0.f};

    for (int kc = 0; kc < 3; ++kc) {
        __syncthreads();
        #pragma unroll
        for (int p = tid; p < 1024; p += 256) {       // A: 4 float4/thread
            const int row = p >> 4, c = p & 15;
            const int off = (row << 8) + ((c << 4) ^ ((row & 7) << 4));
            float4 v = make_float4(0.f, 0.f, 0.f, 0.f);
            if (m0 + row < M)
                v = *(const float4*)(agg + (size_t)(m0 + row) * 384 + kc * 128 + c * 8);
            *(float4*)(As + off) = v;
        }
        #pragma unroll
        for (int p = tid; p < 2048; p += 256) {       // B: 8 float4/thread
            const int row = p >> 4, c = p & 15;
            const int off = (row << 8) + ((c << 4) ^ ((row & 7) << 4));
            *(float4*)(Bs + off) = *(const float4*)(GT + (size_t)row * 384 + kc * 128 + c * 8);
        }
        __syncthreads();
        f16x8 afr[4];
        #pragma unroll
        for (int ks = 0; ks < 4; ++ks)
            afr[ks] = *(const f16x8*)(As + ((wm0 + lrow) << 8) + (((ks << 6) + kslot) ^ swz));
        #pragma unroll
        for (int nf = 0; nf < 8; ++nf) {
            #pragma unroll
            for (int ks = 0; ks < 4; ++ks) {
                f16x8 bfr = *(const f16x8*)(Bs + ((nf * 16 + lrow) << 8) + (((ks << 6) + kslot) ^ swz));
                acc[nf] = __builtin_amdgcn_mfma_f32_16x16x32_f16(afr[ks], bfr, acc[nf], 0, 0, 0);
            }
        }
    }

    // ---- epilogue: bias + ReLU + store f32 + BN column stats (sharded) ----
    float s[8], s2[8], bv[8];
    #pragma unroll
    for (int nf = 0; nf < 8; ++nf) { s[nf] = 0.f; s2[nf] = 0.f; bv[nf] = bias[nf * 16 + lrow]; }
    #pragma unroll
    for (int nf = 0; nf < 8; ++nf)
        #pragma unroll
        for (int rg = 0; rg < 4; ++rg) {
            const int row = m0 + wm0 + (lane >> 4) * 4 + rg;
            if (row < M) {
                const float v = fmaxf(acc[nf][rg] + bv[nf], 0.f);
                out[(size_t)row * FEAT + nf * 16 + lrow] = v;
                s[nf] += v;
                s2[nf] = fmaf(v, v, s2[nf]);
            }
        }
    #pragma unroll
    for (int nf = 0; nf < 8; ++nf) {
        s[nf]  += __shfl_xor(s[nf], 16);  s[nf]  += __shfl_xor(s[nf], 32);
        s2[nf] += __shfl_xor(s2[nf], 16); s2[nf] += __shfl_xor(s2[nf], 32);
    }
    __syncthreads();
    float* red = (float*)smem;                // [4][256]
    if (lane < 16) {
        #pragma unroll
        for (int nf = 0; nf < 8; ++nf) {
            red[wave * 256 + nf * 16 + lane]       = s[nf];
            red[wave * 256 + 128 + nf * 16 + lane] = s2[nf];
        }
    }
    __syncthreads();
    if (tid < 128) {
        const float ss = red[tid] + red[256 + tid] + red[512 + tid] + red[768 + tid];
        const float qq = red[128 + tid] + red[384 + tid] + red[640 + tid] + red[896 + tid];
        float* sb = sbuf + (blockIdx.x & (NSHARD - 1)) * 256;
        atomicAdd(sb + tid, ss);
        atomicAdd(sb + FEAT + tid, qq);
    }
}

// ---- BN normalize (sums the 16 stat shards, derives scale/shift) ----
__global__ void normalize(float* __restrict__ y, const float* __restrict__ sbuf,
                          const float* __restrict__ gamma, const float* __restrict__ beta) {
    __shared__ float sc_s[FEAT], sh_s[FEAT];
    const int t = threadIdx.x;
    if (t < FEAT) {
        float ssum = 0.f, qsum = 0.f;
        #pragma unroll
        for (int sh = 0; sh < NSHARD; ++sh) {
            ssum += sbuf[sh * 256 + t];
            qsum += sbuf[sh * 256 + 128 + t];
        }
        const float mean = ssum / (float)N_NODES;
        const float var  = qsum / (float)N_NODES - mean * mean;
        const float sc   = gamma[t] * rsqrtf(var + BN_EPS);
        sc_s[t] = sc;
        sh_s[t] = beta[t] - mean * sc;
    }
    __syncthreads();
    const int idx = blockIdx.x * blockDim.x + t;
    const int o4 = (idx & 31) * 4;
    float4 v = *(float4*)(y + (size_t)idx * 4);
    const float4 sc = *(const float4*)(sc_s + o4);
    const float4 sh = *(const float4*)(sh_s + o4);
    v.x = fmaf(v.x, sc.x, sh.x);
    v.y = fmaf(v.y, sc.y, sh.y);
    v.z = fmaf(v.z, sc.z, sh.z);
    v.w = fmaf(v.w, sc.w, sh.w);
    *(float4*)(y + (size_t)idx * 4) = v;
}

extern "C" void kernel_launch(void* const* d_in, const int* in_sizes, int n_in,
                              void* d_out, int out_size, void* d_ws, size_t ws_size,
                              hipStream_t stream) {
    const float* feature = (const float*)d_in[0];
    const float* coords  = (const float*)d_in[1];
    const int*   src     = (const int*)d_in[2];
    const int*   dst     = (const int*)d_in[3];
    const int*   order   = (const int*)d_in[4];
    const float* linear  = (const float*)d_in[5];
    const float* attW    = (const float*)d_in[6];
    const float* mlp_w   = (const float*)d_in[7];
    const float* mlp_b   = (const float*)d_in[8];
    const float* gamma   = (const float*)d_in[9];
    const float* beta    = (const float*)d_in[10];
    float* out = (float*)d_out;

    char* p = (char*)d_ws;
    __fp16* fh           = (__fp16*)p;  p += (size_t)N_NODES * FEAT * 2;   // 12.8 MB
    __fp16* agg          = (__fp16*)p;  p += (size_t)N_NODES * 384 * 2;    // 38.4 MB
    __fp16* GT           = (__fp16*)p;  p += (size_t)FEAT * 384 * 2;       // 98 KB
    float4* pk           = (float4*)p;  p += (size_t)N_NODES * 32;         // 1.6 MB
    int*   sord_p        = (int*)p;     p += (size_t)E_EDGES * 4;          // 3.2 MB
    int2*  bbuf          = (int2*)p;    p += (size_t)NBUK * BCAP * 8;      // 8.0 MB
    int*   cnt           = (int*)p;     p += 200064;
    float* sbuf          = (float*)p;   p += NSHARD * 256 * 4;             // 16 KB
    int*   gcur          = (int*)p;     p += 1024;   // memset covers cnt+sbuf+gcur
    int*   rowptr        = (int*)p;     p += 200064;
    int*   cursor        = (int*)p;     p += 200064;
    int*   bsum          = (int*)p;     p += 256;
    int*   boff          = (int*)p;     p += 256;

    hipMemsetAsync(cnt, 0, 200064 + NSHARD * 256 * 4 + 1024, stream);

    const int NWB = (N_NODES * 64) / 256;         // 12500
    const int MB  = (N_NODES + 63) / 64;          // 782
    const int AB  = (E_EDGES + 2047) / 2048;      // 391

    gprep<<<FEAT, FEAT, 0, stream>>>(mlp_w, linear, GT);
    g_cast<<<NWB, 256, 0, stream>>>(feature, coords, attW, fh, pk);

    bucketA<<<AB, 256, 0, stream>>>(src, dst, order, cnt, gcur, bbuf);
    scan1<<<NB1, 256, 0, stream>>>(cnt, rowptr, bsum);
    scan2<<<1, 64, 0, stream>>>(bsum, boff, rowptr);
    scan3<<<(N_NODES + 255) / 256, 256, 0, stream>>>(rowptr, cursor, boff);
    bucketB<<<NBUK * 8, 256, 0, stream>>>(gcur, bbuf, cursor, sord_p);

    segagg<<<NWB, 256, 0, stream>>>(pk, sord_p, rowptr, fh, agg);

    mlp_gemm<<<MB, 256, 0, stream>>>(agg, GT, out, N_NODES, mlp_b, sbuf);
    normalize<<<(N_NODES * 32) / 256, 256, 0, stream>>>(out, sbuf, gamma, beta);
}